// Round 12
// baseline (390.850 us; speedup 1.0000x reference)
//
#include <hip/hip_runtime.h>
#include <hip/hip_bf16.h>
#include <math.h>

#define DD 128

typedef __attribute__((ext_vector_type(8))) short short8;
typedef __attribute__((ext_vector_type(4))) float f32x4;
typedef __attribute__((ext_vector_type(2))) float f32x2;

static __device__ __forceinline__ unsigned short f2bf(float f) {
    unsigned u = __float_as_uint(f);
    u += 0x7fffu + ((u >> 16) & 1u);   // RNE
    return (unsigned short)(u >> 16);
}
static __device__ __forceinline__ float bflo(unsigned mm) { return __uint_as_float(mm << 16); }
static __device__ __forceinline__ float bfhi(unsigned mm) { return __uint_as_float(mm & 0xffff0000u); }
// unpack a dword of 2 bf16 into packed f32x2 (feeds v_pk_fma_f32)
static __device__ __forceinline__ f32x2 unpk(unsigned w) {
    f32x2 r; r.x = __uint_as_float(w << 16); r.y = __uint_as_float(w & 0xffff0000u);
    return r;
}

static __device__ __forceinline__ f32x4 MFMA(short8 a, short8 b, f32x4 c) {
    return __builtin_amdgcn_mfma_f32_16x16x32_bf16(a, b, c, 0, 0, 0);
}
// involution swizzle on 16B-unit index: spreads A-frag writer banks, reader stays conflict-free
static __device__ __forceinline__ int uswz(int u) { return u ^ ((u >> 4) & 7); }

// diagnostic marker fill
__global__ void k_fill(float* __restrict__ out, float v, int n) {
    int i = blockIdx.x * 256 + threadIdx.x;
    if (i < n) out[i] = v;
}

// ---------------------------------------------------------------------------
// fused prep: blocks 0..127   -> M[c][j] = sum_k Wq[k][c]*Wk[k][j] in MFMA
//                                B-fragment order, bf16 hi/lo (Bh/Bl)
//             blocks 128..130 -> u_r/v_r folds
//             blocks 131..    -> zero CSR counters + scan cursor (NZ words)
__global__ void k_prep(const float* __restrict__ Wq, const float* __restrict__ Wk,
                       const float* __restrict__ W10, const float* __restrict__ W11,
                       const float* __restrict__ W12,
                       const float* __restrict__ w20, const float* __restrict__ w21,
                       const float* __restrict__ w22,
                       unsigned short* __restrict__ Bh, unsigned short* __restrict__ Bl,
                       float* __restrict__ uv, unsigned* __restrict__ cnt, int NZ) {
    int b = blockIdx.x, j = threadIdx.x;
    if (b < DD) {
        float acc = 0.f;
        for (int k = 0; k < DD; ++k)
            acc += Wq[k*DD + b] * Wk[k*DD + j];
        unsigned short hi = f2bf(acc);
        unsigned short lo = f2bf(acc - bflo(hi));
        // B-frag: lane l holds B[ks*32 + 8*(l>>4) + jj][t*16 + (l&15)], jj=0..7
        int t  = j >> 4;
        int ks = b >> 5;
        int l  = ((b >> 3) & 3) * 16 + (j & 15);
        int jj = b & 7;
        int idx = ((t*4 + ks)*64 + l)*8 + jj;
        Bh[idx] = hi;
        Bl[idx] = lo;
    } else if (b < DD + 3) {
        int r = b - DD;
        const float* W1 = (r==0) ? W10 : (r==1 ? W11 : W12);
        const float* w2 = (r==0) ? w20 : (r==1 ? w21 : w22);
        float u = 0.f, v = 0.f;
        for (int k = 0; k < DD; ++k) {
            float w = W1[k*DD + j];
            u += w2[k]      * w;
            v += w2[DD + k] * w;
        }
        uv[r*256 + j]      = u;
        uv[r*256 + DD + j] = v;
    } else {
        int idx = (b - (DD + 3)) * DD + j;
        if (idx < NZ) cnt[idx] = 0u;   // NZ = SEG+1 (counters + cursor)
    }
}

// ---------------------------------------------------------------------------
// k_scores (+fused count): 2 nodes/wave (half-wave float4) for per-node
// score folds + bf16 N copy; additionally thread g < 3E does the per-edge
// degree count + rank (atomics hide under the N stream). cnt is pre-zeroed
// by k_prep (k_scores already depends on k_prep via uv).
__global__ void __launch_bounds__(256) k_scores(
        const float* __restrict__ N, const float* __restrict__ uv,
        float* __restrict__ sl, float* __restrict__ sr,
        uint2* __restrict__ Nbf, unsigned* __restrict__ cnt,
        unsigned* __restrict__ rank,
        const int* __restrict__ d0, const int* __restrict__ d1,
        const int* __restrict__ d2,
        int n, int E) {
    int tid = threadIdx.x;
    int g = blockIdx.x * 256 + tid;
    if (g < 3*E) {                       // fused k_count
        int r = (g >= 2*E) ? 2 : (g >= E ? 1 : 0);
        int e = g - r*E;
        const int* Dd = (r==0) ? d0 : (r==1 ? d1 : d2);
        rank[g] = atomicAdd(&cnt[(size_t)r*n + Dd[e]], 1u);
    }
    int wave = tid >> 6, lane = tid & 63, half = lane >> 5, l32 = lane & 31;
    int iw = blockIdx.x * 8 + wave * 2 + half;
    if (iw >= n && blockIdx.x * 8 >= n) return;   // pure-count tail blocks
    int i = (iw < n) ? iw : (n - 1);
    float4 nv = ((const float4*)N)[(size_t)i * 32 + l32];
    if (iw < n) {
        uint2 pk;
        pk.x = (unsigned)f2bf(nv.x) | ((unsigned)f2bf(nv.y) << 16);
        pk.y = (unsigned)f2bf(nv.z) | ((unsigned)f2bf(nv.w) << 16);
        Nbf[(size_t)iw * 32 + l32] = pk;
    }
    const float4* UV4 = (const float4*)uv;
    float acc[6];
#pragma unroll
    for (int r = 0; r < 3; ++r) {
        float4 u = UV4[r*64 + l32];
        float4 v = UV4[r*64 + 32 + l32];
        acc[2*r]   = nv.x*u.x + nv.y*u.y + nv.z*u.z + nv.w*u.w;
        acc[2*r+1] = nv.x*v.x + nv.y*v.y + nv.z*v.z + nv.w*v.w;
    }
#pragma unroll
    for (int o = 16; o; o >>= 1) {
#pragma unroll
        for (int q = 0; q < 6; ++q) acc[q] += __shfl_xor(acc[q], o);
    }
    if (l32 == 0 && iw < n) {
#pragma unroll
        for (int r = 0; r < 3; ++r) {
            sl[(size_t)r*n + iw] = acc[2*r];
            sr[(size_t)r*n + iw] = acc[2*r+1];
        }
    }
}

// ---------------------------------------------------------------------------
// k_scanA: ONE-kernel segment allocation. Each block scans its 256-segment
// tile locally, then claims a contiguous edat range with a single
// atomicAdd(cursor, tileTotal). off[] becomes ABSOLUTE; per-segment counts
// are preserved in cnts[]. Output bit-identical (segment placement permutes,
// within-segment order unchanged).
__global__ void __launch_bounds__(256) k_scanA(unsigned* __restrict__ off,
                                               unsigned* __restrict__ cnts,
                                               unsigned* __restrict__ cursor,
                                               int SEG) {
    __shared__ unsigned s[256];
    __shared__ unsigned base;
    int tid = threadIdx.x;
    int i = blockIdx.x * 256 + tid;
    unsigned v = (i < SEG) ? off[i] : 0u;
    s[tid] = v; __syncthreads();
#pragma unroll
    for (int o = 1; o < 256; o <<= 1) {
        unsigned a = (tid >= o) ? s[tid - o] : 0u; __syncthreads();
        s[tid] += a; __syncthreads();
    }
    if (tid == 255) base = atomicAdd(cursor, s[255]);
    __syncthreads();
    if (i < SEG) {
        off[i]  = base + s[tid] - v;   // absolute exclusive offset
        cnts[i] = v;                   // per-segment count
    }
}

// scatter with precomputed rank — no atomics; off[] is absolute
__global__ void k_scatter(const int* __restrict__ s0, const int* __restrict__ d0,
                          const int* __restrict__ s1, const int* __restrict__ d1,
                          const int* __restrict__ s2, const int* __restrict__ d2,
                          const float* __restrict__ sl, const float* __restrict__ sr,
                          const unsigned* __restrict__ off,
                          const unsigned* __restrict__ rank,
                          uint2* __restrict__ edat, int n, int E) {
    int g = blockIdx.x * 256 + threadIdx.x;
    if (g >= 3*E) return;
    int r = (g >= 2*E) ? 2 : (g >= E ? 1 : 0);
    int e = g - r*E;
    const int* S  = (r==0) ? s0 : (r==1 ? s1 : s2);
    const int* Dd = (r==0) ? d0 : (r==1 ? d1 : d2);
    int si = S[e], di = Dd[e];
    int seg = r*n + di;
    float x = sl[(size_t)r*n + si] + sr[seg];
    x = (x >= 0.f) ? x : 0.01f * x;            // leaky_relu
    unsigned p = off[seg] + rank[g];
    edat[p] = make_uint2((unsigned)si, __float_as_uint(x));
}

// ---------------------------------------------------------------------------
// k_node: fused per-node pass, 256 threads, FOUR nodes per wave (one per
// 16-lane group) -> 16 nodes/block. [R11 base — proven 105us] + RELATION-
// INTERLEAVED gather: the 3 relations' (independent) gather loops now run
// in ONE loop over max(C[r]) with group-uniform guards -> up to 12 row
// loads in flight per group instead of 4, same unroll depth. Per-relation
// accumulation order unchanged -> bit-identical. (256,4) bound leaves the
// allocator VGPR room (R10 lesson: the (256,8)=32-VGPR pin caused R8's
// spill, not the ILP itself).
__global__ void __launch_bounds__(256, 4) k_node(
        const uint4* __restrict__ Nbf,
        const uint4* __restrict__ B4h, const uint4* __restrict__ B4l,
        const unsigned* __restrict__ off,
        const unsigned* __restrict__ cnts,
        const uint2* __restrict__ edat,
        const int* __restrict__ tgt,
        float* __restrict__ out, int n) {
    __shared__ uint4 afrag[2][256];      // A-fragments (h_t hi/lo), 8 KB
    __shared__ float Tl[16*132];         // T = H_t M, stride 132 vs banks, 8.25 KB
    int tid = threadIdx.x;
    int wave = tid >> 6, lane = tid & 63;
    int grp = lane >> 4;                 // node within wave (0..3)
    int l16 = lane & 15;
    int nid = wave * 4 + grp;            // node row 0..15
    int iw = blockIdx.x * 16 + nid;      // true node id
    int i = (iw < n) ? iw : (n - 1);     // clamped for safe addressing
    int t = tgt[0];
    t = (t < 0) ? 0 : (t > 2 ? 2 : t);

    // hoist all 3 relations' CSR ranges (uniform within each 16-lane group)
    int A[3], C[3];
#pragma unroll
    for (int r = 0; r < 3; ++r) {
        int seg = r*n + i;
        A[r] = (int)off[seg];
        C[r] = (int)cnts[seg];
    }

    // softmax stats for all 3 relations (per group; xor<=8 stays in-group)
    float m_[3], inv_[3];
#pragma unroll
    for (int r = 0; r < 3; ++r) {
        int cc = C[r];
        float m, s;
        if (cc <= 16) {
            float x = (l16 < cc) ? __uint_as_float(edat[A[r] + l16].y) : -INFINITY;
            m = x;
#pragma unroll
            for (int o = 8; o; o >>= 1) m = fmaxf(m, __shfl_xor(m, o));
            s = (l16 < cc) ? __expf(x - m) : 0.f;
#pragma unroll
            for (int o = 8; o; o >>= 1) s += __shfl_xor(s, o);
        } else {
            m = -INFINITY;
            for (int j = A[r] + l16; j < A[r] + cc; j += 16)
                m = fmaxf(m, __uint_as_float(edat[j].y));
#pragma unroll
            for (int o = 8; o; o >>= 1) m = fmaxf(m, __shfl_xor(m, o));
            s = 0.f;
            for (int j = A[r] + l16; j < A[r] + cc; j += 16)
                s += __expf(__uint_as_float(edat[j].y) - m);
#pragma unroll
            for (int o = 8; o; o >>= 1) s += __shfl_xor(s, o);
        }
        m_[r] = m; inv_[r] = 1.f / s;    // cc==0: unused (gather loop skipped)
    }

    // relation-interleaved gather, x4 per relation per iteration.
    // h2[r][k] indices are static (unrolled r,k) — no scratch (rule #20).
    f32x2 h2[3][4];
#pragma unroll
    for (int r = 0; r < 3; ++r)
#pragma unroll
        for (int k = 0; k < 4; ++k) h2[r][k] = (f32x2){0.f, 0.f};
    int ccm = C[0];
    if (C[1] > ccm) ccm = C[1];
    if (C[2] > ccm) ccm = C[2];
    for (int p = 0; p < ccm; p += 4) {
#pragma unroll
        for (int r = 0; r < 3; ++r) {
            int cc = C[r];
            if (p < cc) {
                int a = A[r];
                float mm = m_[r], iv = inv_[r];
                int e1 = (p + 1 < cc) ? p + 1 : cc - 1;
                int e2 = (p + 2 < cc) ? p + 2 : cc - 1;
                int e3 = (p + 3 < cc) ? p + 3 : cc - 1;
                uint2 ed0 = edat[a + p];
                uint2 ed1 = edat[a + e1];
                uint2 ed2 = edat[a + e2];
                uint2 ed3 = edat[a + e3];
                uint4 v0 = Nbf[(size_t)ed0.x * 16 + l16];
                uint4 v1 = Nbf[(size_t)ed1.x * 16 + l16];
                uint4 v2 = Nbf[(size_t)ed2.x * 16 + l16];
                uint4 v3 = Nbf[(size_t)ed3.x * 16 + l16];
                float a0 = __expf(__uint_as_float(ed0.y) - mm) * iv;
                float a1 = (p + 1 < cc) ? __expf(__uint_as_float(ed1.y) - mm) * iv : 0.f;
                float a2 = (p + 2 < cc) ? __expf(__uint_as_float(ed2.y) - mm) * iv : 0.f;
                float a3 = (p + 3 < cc) ? __expf(__uint_as_float(ed3.y) - mm) * iv : 0.f;
                f32x2 A0 = (f32x2){a0, a0}, A1 = (f32x2){a1, a1};
                f32x2 A2 = (f32x2){a2, a2}, A3 = (f32x2){a3, a3};
                h2[r][0] += A0*unpk(v0.x) + A1*unpk(v1.x) + A2*unpk(v2.x) + A3*unpk(v3.x);
                h2[r][1] += A0*unpk(v0.y) + A1*unpk(v1.y) + A2*unpk(v2.y) + A3*unpk(v3.y);
                h2[r][2] += A0*unpk(v0.z) + A1*unpk(v1.z) + A2*unpk(v2.z) + A3*unpk(v3.z);
                h2[r][3] += A0*unpk(v0.w) + A1*unpk(v1.w) + A2*unpk(v2.w) + A3*unpk(v3.w);
            }
        }
    }

    // lane l16 owns dims 8*l16..+7 of its node — no cross-group reduce
    float hr[3][8];
#pragma unroll
    for (int r = 0; r < 3; ++r)
#pragma unroll
        for (int k = 0; k < 4; ++k) {
            hr[r][2*k]   = h2[r][k].x;
            hr[r][2*k+1] = h2[r][k].y;
        }

    // A-fragment write (h_t hi/lo, fragment order), node-row = nid;
    // unrolled r with runtime compare keeps indexing static.
#pragma unroll
    for (int r = 0; r < 3; ++r) {
        if (r == t) {
            unsigned ph[4], pl[4];
#pragma unroll
            for (int k = 0; k < 4; ++k) {
                unsigned short h0 = f2bf(h2[r][k].x);
                unsigned short h1 = f2bf(h2[r][k].y);
                unsigned short g0 = f2bf(h2[r][k].x - bflo(h0));
                unsigned short g1 = f2bf(h2[r][k].y - bflo(h1));
                ph[k] = (unsigned)h0 | ((unsigned)h1 << 16);
                pl[k] = (unsigned)g0 | ((unsigned)g1 << 16);
            }
            int u = uswz(((l16 >> 2) * 64) + ((l16 & 3) * 16) + nid);
            afrag[0][u] = make_uint4(ph[0], ph[1], ph[2], ph[3]);
            afrag[1][u] = make_uint4(pl[0], pl[1], pl[2], pl[3]);
        }
    }
    __syncthreads();

    // T = Ah*Bh + Al*Bh + Ah*Bl ; wave w owns j-tiles 2w, 2w+1.
    {
        int qm = lane >> 4;              // C/D row group 0..3
        f32x4 acc0 = {0.f, 0.f, 0.f, 0.f};
        f32x4 acc1 = {0.f, 0.f, 0.f, 0.f};
        int jt0 = wave*2, jt1 = wave*2 + 1;
        for (int ks = 0; ks < 4; ++ks) {
            uint4 a_hi = afrag[0][uswz(ks*64 + lane)];
            uint4 a_lo = afrag[1][uswz(ks*64 + lane)];
            uint4 b0h = B4h[(jt0*4 + ks)*64 + lane];
            uint4 b0l = B4l[(jt0*4 + ks)*64 + lane];
            uint4 b1h = B4h[(jt1*4 + ks)*64 + lane];
            uint4 b1l = B4l[(jt1*4 + ks)*64 + lane];
            acc0 = MFMA(__builtin_bit_cast(short8, a_hi),
                        __builtin_bit_cast(short8, b0h), acc0);
            acc1 = MFMA(__builtin_bit_cast(short8, a_hi),
                        __builtin_bit_cast(short8, b1h), acc1);
            acc0 = MFMA(__builtin_bit_cast(short8, a_lo),
                        __builtin_bit_cast(short8, b0h), acc0);
            acc1 = MFMA(__builtin_bit_cast(short8, a_lo),
                        __builtin_bit_cast(short8, b1h), acc1);
            acc0 = MFMA(__builtin_bit_cast(short8, a_hi),
                        __builtin_bit_cast(short8, b0l), acc0);
            acc1 = MFMA(__builtin_bit_cast(short8, a_hi),
                        __builtin_bit_cast(short8, b1l), acc1);
        }
        // C/D layout: col = lane&15, row = (lane>>4)*4 + reg  [verified]
        int col0 = jt0*16 + l16, col1 = jt1*16 + l16;
#pragma unroll
        for (int rg = 0; rg < 4; ++rg) {
            Tl[(qm*4 + rg)*132 + col0] = acc0[rg];
            Tl[(qm*4 + rg)*132 + col1] = acc1[rg];
        }
    }
    __syncthreads();

    // each group reads its node's T row: lane l16 -> dims 8*l16..+7
    float4 ta = *(const float4*)&Tl[nid*132 + 8*l16];
    float4 tb = *(const float4*)&Tl[nid*132 + 8*l16 + 4];
    float t8[8] = {ta.x, ta.y, ta.z, ta.w, tb.x, tb.y, tb.z, tb.w};

    const float inv = 0.088388347648318447f;   // 1/sqrt(128)
    float e[3];
#pragma unroll
    for (int r = 0; r < 3; ++r) {
        float v = 0.f;
#pragma unroll
        for (int k = 0; k < 8; ++k) v += t8[k]*hr[r][k];
#pragma unroll
        for (int o = 8; o; o >>= 1) v += __shfl_xor(v, o);   // over l16
        e[r] = v * inv;
    }
    float mx = fmaxf(e[0], fmaxf(e[1], e[2]));
    float x0 = __expf(e[0]-mx), x1 = __expf(e[1]-mx), x2 = __expf(e[2]-mx);
    float sinv = 1.f / (x0 + x1 + x2);
    float aw0 = x0*sinv, aw1 = x1*sinv, aw2 = x2*sinv;
    if (iw < n) {
        float4 oa, ob;
        oa.x = aw0*hr[0][0] + aw1*hr[1][0] + aw2*hr[2][0];
        oa.y = aw0*hr[0][1] + aw1*hr[1][1] + aw2*hr[2][1];
        oa.z = aw0*hr[0][2] + aw1*hr[1][2] + aw2*hr[2][2];
        oa.w = aw0*hr[0][3] + aw1*hr[1][3] + aw2*hr[2][3];
        ob.x = aw0*hr[0][4] + aw1*hr[1][4] + aw2*hr[2][4];
        ob.y = aw0*hr[0][5] + aw1*hr[1][5] + aw2*hr[2][5];
        ob.z = aw0*hr[0][6] + aw1*hr[1][6] + aw2*hr[2][6];
        ob.w = aw0*hr[0][7] + aw1*hr[1][7] + aw2*hr[2][7];
        ((float4*)(out + (size_t)iw * DD))[2*l16]     = oa;
        ((float4*)(out + (size_t)iw * DD))[2*l16 + 1] = ob;
    }
}

// ---------------------------------------------------------------------------
extern "C" void kernel_launch(void* const* d_in, const int* in_sizes, int n_in,
                              void* d_out, int out_size, void* d_ws, size_t ws_size,
                              hipStream_t stream) {
    float* outp = (float*)d_out;
    int fillgrid = (out_size + 255) / 256;
    if (n_in != 17) {                                  // marker: 1024.0
        k_fill<<<fillgrid, 256, 0, stream>>>(outp, 1024.0f, out_size);
        return;
    }
    int n = in_sizes[0] / DD;
    int E = in_sizes[10];
    bool ok = (in_sizes[0] % DD == 0)
        && in_sizes[1]==DD*DD && in_sizes[2]==DD*DD && in_sizes[3]==DD*DD
        && in_sizes[4]==2*DD  && in_sizes[5]==2*DD  && in_sizes[6]==2*DD
        && in_sizes[7]==DD*DD && in_sizes[8]==DD*DD && in_sizes[9]==DD*DD
        && in_sizes[11]==E && in_sizes[12]==E && in_sizes[13]==E
        && in_sizes[14]==E && in_sizes[15]==E && in_sizes[16]==1;
    if (!ok) {                                         // marker: 512.0
        k_fill<<<fillgrid, 256, 0, stream>>>(outp, 512.0f, out_size);
        return;
    }
    int SEG = 3*n;
    int NB1 = (SEG + 255) / 256;
    int tot = 3*E;

    // ws (floats): sl[3n] sr[3n] uv[768] Bh+Bl[DD*DD floats as ushort]
    //              off[3n] cursor[1] cnts[3n] rank[3E]
    //              | edat[3E]x2 (8B) | Nbf[n*64] (16B)
    size_t o_edat = (size_t)2*SEG + 768 + DD*DD + (size_t)SEG + 1 + (size_t)SEG
                  + (size_t)tot;
    o_edat = (o_edat + 1) & ~(size_t)1;
    size_t o_nbf = o_edat + (size_t)2*tot;
    o_nbf = (o_nbf + 3) & ~(size_t)3;
    size_t need_f = o_nbf + (size_t)n*64;
    if (ws_size < need_f * sizeof(float)) {            // marker: 256.0
        k_fill<<<fillgrid, 256, 0, stream>>>(outp, 256.0f, out_size);
        return;
    }

    const float* N   = (const float*)d_in[0];
    const float* W10 = (const float*)d_in[1];
    const float* W11 = (const float*)d_in[2];
    const float* W12 = (const float*)d_in[3];
    const float* w20 = (const float*)d_in[4];
    const float* w21 = (const float*)d_in[5];
    const float* w22 = (const float*)d_in[6];
    const float* Wq  = (const float*)d_in[7];
    const float* Wk  = (const float*)d_in[8];
    // d_in[9] = Wv — unused in the reference output
    const int* s0 = (const int*)d_in[10];
    const int* d0 = (const int*)d_in[11];
    const int* s1 = (const int*)d_in[12];
    const int* d1 = (const int*)d_in[13];
    const int* s2 = (const int*)d_in[14];
    const int* d2 = (const int*)d_in[15];
    const int* tgt = (const int*)d_in[16];

    float* ws = (float*)d_ws;
    float* sl = ws;
    float* sr = sl + SEG;
    float* uv = sr + SEG;
    unsigned short* Bh = (unsigned short*)(uv + 768);   // 16384 bf16 (32 KB)
    unsigned short* Bl = Bh + DD*DD;                    // 16384 bf16 (32 KB)
    unsigned* off    = (unsigned*)(uv + 768 + DD*DD);   // counters -> abs offsets
    unsigned* cursor = off + SEG;                       // 1 word (zeroed with off)
    unsigned* cnts   = cursor + 1;                      // per-segment counts
    unsigned* rank   = cnts + SEG;
    uint2*    edat = (uint2*)(ws + o_edat);
    unsigned* Nbf  = (unsigned*)(ws + o_nbf);

    int NZ  = SEG + 1;                                 // zero off + cursor
    int NBZ = (NZ + DD - 1) / DD;
    int gridS = (n + 7) / 8;                           // score blocks
    int gridC = (tot + 255) / 256;                     // count threads coverage
    if (gridC > gridS) gridS = gridC;

    k_prep<<<DD + 3 + NBZ, DD, 0, stream>>>(Wq, Wk, W10, W11, W12,
                                            w20, w21, w22, Bh, Bl, uv, off, NZ);
    k_scores<<<gridS, 256, 0, stream>>>(N, uv, sl, sr, (uint2*)Nbf, off, rank,
                                        d0, d1, d2, n, E);
    k_scanA<<<NB1, 256, 0, stream>>>(off, cnts, cursor, SEG);
    k_scatter<<<(tot + 255)/256, 256, 0, stream>>>(s0,d0,s1,d1,s2,d2, sl,sr,
                                                   off, rank, edat, n, E);
    k_node<<<(n + 15)/16, 256, 0, stream>>>((const uint4*)Nbf,
                                            (const uint4*)Bh, (const uint4*)Bl,
                                            off, cnts, edat, tgt, outp, n);
}

// Round 13
// 371.098 us; speedup vs baseline: 1.0532x; 1.0532x over previous
//
#include <hip/hip_runtime.h>
#include <hip/hip_bf16.h>
#include <math.h>

#define DD 128

typedef __attribute__((ext_vector_type(8))) short short8;
typedef __attribute__((ext_vector_type(4))) float f32x4;
typedef __attribute__((ext_vector_type(2))) float f32x2;

static __device__ __forceinline__ unsigned short f2bf(float f) {
    unsigned u = __float_as_uint(f);
    u += 0x7fffu + ((u >> 16) & 1u);   // RNE
    return (unsigned short)(u >> 16);
}
static __device__ __forceinline__ float bflo(unsigned mm) { return __uint_as_float(mm << 16); }
static __device__ __forceinline__ float bfhi(unsigned mm) { return __uint_as_float(mm & 0xffff0000u); }
// unpack a dword of 2 bf16 into packed f32x2 (feeds v_pk_fma_f32)
static __device__ __forceinline__ f32x2 unpk(unsigned w) {
    f32x2 r; r.x = __uint_as_float(w << 16); r.y = __uint_as_float(w & 0xffff0000u);
    return r;
}

static __device__ __forceinline__ f32x4 MFMA(short8 a, short8 b, f32x4 c) {
    return __builtin_amdgcn_mfma_f32_16x16x32_bf16(a, b, c, 0, 0, 0);
}
// involution swizzle on 16B-unit index: spreads A-frag writer banks, reader stays conflict-free
static __device__ __forceinline__ int uswz(int u) { return u ^ ((u >> 4) & 7); }

// diagnostic marker fill
__global__ void k_fill(float* __restrict__ out, float v, int n) {
    int i = blockIdx.x * 256 + threadIdx.x;
    if (i < n) out[i] = v;
}

// ---------------------------------------------------------------------------
// fused prep: blocks 0..127   -> M[c][j] = sum_k Wq[k][c]*Wk[k][j] in MFMA
//                                B-fragment order, bf16 hi/lo (Bh/Bl)
//             blocks 128..130 -> u_r/v_r folds
//             blocks 131..    -> zero CSR counters (SEG words)
__global__ void k_prep(const float* __restrict__ Wq, const float* __restrict__ Wk,
                       const float* __restrict__ W10, const float* __restrict__ W11,
                       const float* __restrict__ W12,
                       const float* __restrict__ w20, const float* __restrict__ w21,
                       const float* __restrict__ w22,
                       unsigned short* __restrict__ Bh, unsigned short* __restrict__ Bl,
                       float* __restrict__ uv, unsigned* __restrict__ cnt, int NZ) {
    int b = blockIdx.x, j = threadIdx.x;
    if (b < DD) {
        float acc = 0.f;
        for (int k = 0; k < DD; ++k)
            acc += Wq[k*DD + b] * Wk[k*DD + j];
        unsigned short hi = f2bf(acc);
        unsigned short lo = f2bf(acc - bflo(hi));
        // B-frag: lane l holds B[ks*32 + 8*(l>>4) + jj][t*16 + (l&15)], jj=0..7
        int t  = j >> 4;
        int ks = b >> 5;
        int l  = ((b >> 3) & 3) * 16 + (j & 15);
        int jj = b & 7;
        int idx = ((t*4 + ks)*64 + l)*8 + jj;
        Bh[idx] = hi;
        Bl[idx] = lo;
    } else if (b < DD + 3) {
        int r = b - DD;
        const float* W1 = (r==0) ? W10 : (r==1 ? W11 : W12);
        const float* w2 = (r==0) ? w20 : (r==1 ? w21 : w22);
        float u = 0.f, v = 0.f;
        for (int k = 0; k < DD; ++k) {
            float w = W1[k*DD + j];
            u += w2[k]      * w;
            v += w2[DD + k] * w;
        }
        uv[r*256 + j]      = u;
        uv[r*256 + DD + j] = v;
    } else {
        int idx = (b - (DD + 3)) * DD + j;
        if (idx < NZ) cnt[idx] = 0u;
    }
}

// ---------------------------------------------------------------------------
// k_scores (+fused count): 2 nodes/wave (half-wave float4) for per-node
// score folds + bf16 N copy; additionally thread g < 3E does the per-edge
// degree count + rank (atomics hide under the N stream). cnt is pre-zeroed
// by k_prep (k_scores already depends on k_prep via uv).
__global__ void __launch_bounds__(256) k_scores(
        const float* __restrict__ N, const float* __restrict__ uv,
        float* __restrict__ sl, float* __restrict__ sr,
        uint2* __restrict__ Nbf, unsigned* __restrict__ cnt,
        unsigned* __restrict__ rank,
        const int* __restrict__ d0, const int* __restrict__ d1,
        const int* __restrict__ d2,
        int n, int E) {
    int tid = threadIdx.x;
    int g = blockIdx.x * 256 + tid;
    if (g < 3*E) {                       // fused k_count
        int r = (g >= 2*E) ? 2 : (g >= E ? 1 : 0);
        int e = g - r*E;
        const int* Dd = (r==0) ? d0 : (r==1 ? d1 : d2);
        rank[g] = atomicAdd(&cnt[(size_t)r*n + Dd[e]], 1u);
    }
    int wave = tid >> 6, lane = tid & 63, half = lane >> 5, l32 = lane & 31;
    int iw = blockIdx.x * 8 + wave * 2 + half;
    if (iw >= n && blockIdx.x * 8 >= n) return;   // pure-count tail blocks
    int i = (iw < n) ? iw : (n - 1);
    float4 nv = ((const float4*)N)[(size_t)i * 32 + l32];
    if (iw < n) {
        uint2 pk;
        pk.x = (unsigned)f2bf(nv.x) | ((unsigned)f2bf(nv.y) << 16);
        pk.y = (unsigned)f2bf(nv.z) | ((unsigned)f2bf(nv.w) << 16);
        Nbf[(size_t)iw * 32 + l32] = pk;
    }
    const float4* UV4 = (const float4*)uv;
    float acc[6];
#pragma unroll
    for (int r = 0; r < 3; ++r) {
        float4 u = UV4[r*64 + l32];
        float4 v = UV4[r*64 + 32 + l32];
        acc[2*r]   = nv.x*u.x + nv.y*u.y + nv.z*u.z + nv.w*u.w;
        acc[2*r+1] = nv.x*v.x + nv.y*v.y + nv.z*v.z + nv.w*v.w;
    }
#pragma unroll
    for (int o = 16; o; o >>= 1) {
#pragma unroll
        for (int q = 0; q < 6; ++q) acc[q] += __shfl_xor(acc[q], o);
    }
    if (l32 == 0 && iw < n) {
#pragma unroll
        for (int r = 0; r < 3; ++r) {
            sl[(size_t)r*n + iw] = acc[2*r];
            sr[(size_t)r*n + iw] = acc[2*r+1];
        }
    }
}

// ---------------------------------------------------------------------------
// k_scan1: per-tile exclusive scan; also emits per-segment counts (cnts)
// so downstream range-hoists need one broadcast load per segment instead
// of reading off[seg+1]. [scanA's global-cursor variant cost +12us on the
// blob (confirmed R11+R12) — reverted to the two-kernel chain.]
__global__ void __launch_bounds__(256) k_scan1(unsigned* __restrict__ off,
                                               unsigned* __restrict__ bsum,
                                               unsigned* __restrict__ cnts,
                                               int SEG) {
    __shared__ unsigned s[256];
    int tid = threadIdx.x;
    int i = blockIdx.x * 256 + tid;
    unsigned v = (i < SEG) ? off[i] : 0u;
    s[tid] = v; __syncthreads();
#pragma unroll
    for (int o = 1; o < 256; o <<= 1) {
        unsigned a = (tid >= o) ? s[tid - o] : 0u; __syncthreads();
        s[tid] += a; __syncthreads();
    }
    if (i < SEG) {
        off[i]  = s[tid] - v;          // exclusive within tile
        cnts[i] = v;                   // per-segment count
    }
    if (tid == 255) bsum[blockIdx.x] = s[255]; // tile total
}

__global__ void __launch_bounds__(256) k_scan2(unsigned* __restrict__ bsum, int nb) {
    __shared__ unsigned s[256];
    __shared__ unsigned carry;
    int tid = threadIdx.x;
    if (tid == 0) carry = 0u;
    for (int base = 0; base < nb; base += 256) {
        int i = base + tid;
        unsigned v = (i < nb) ? bsum[i] : 0u;
        __syncthreads();
        s[tid] = v; __syncthreads();
#pragma unroll
        for (int o = 1; o < 256; o <<= 1) {
            unsigned a = (tid >= o) ? s[tid - o] : 0u; __syncthreads();
            s[tid] += a; __syncthreads();
        }
        unsigned incl = s[tid], tot = s[255], c = carry;
        if (i < nb) bsum[i] = c + incl - v;    // exclusive across tiles
        __syncthreads();
        if (tid == 0) carry = c + tot;
    }
}

// scatter with precomputed rank — no atomics
__global__ void k_scatter(const int* __restrict__ s0, const int* __restrict__ d0,
                          const int* __restrict__ s1, const int* __restrict__ d1,
                          const int* __restrict__ s2, const int* __restrict__ d2,
                          const float* __restrict__ sl, const float* __restrict__ sr,
                          const unsigned* __restrict__ off,
                          const unsigned* __restrict__ bsum,
                          const unsigned* __restrict__ rank,
                          uint2* __restrict__ edat, int n, int E) {
    int g = blockIdx.x * 256 + threadIdx.x;
    if (g >= 3*E) return;
    int r = (g >= 2*E) ? 2 : (g >= E ? 1 : 0);
    int e = g - r*E;
    const int* S  = (r==0) ? s0 : (r==1 ? s1 : s2);
    const int* Dd = (r==0) ? d0 : (r==1 ? d1 : d2);
    int si = S[e], di = Dd[e];
    int seg = r*n + di;
    float x = sl[(size_t)r*n + si] + sr[seg];
    x = (x >= 0.f) ? x : 0.01f * x;            // leaky_relu
    unsigned p = off[seg] + bsum[seg >> 8] + rank[g];
    edat[p] = make_uint2((unsigned)si, __float_as_uint(x));
}

// ---------------------------------------------------------------------------
// k_node: fused per-node pass, 256 threads, FOUR nodes per wave (one per
// 16-lane group) -> 16 nodes/block. [R11's non-interleaved x4 gather under
// __launch_bounds__(256,4) — proven 105us; the R12 relation-interleave
// regressed (serialized guarded bodies) and was reverted.] CSR range:
// base = off+bsum, count = cnts (one broadcast load each).
__global__ void __launch_bounds__(256, 4) k_node(
        const uint4* __restrict__ Nbf,
        const uint4* __restrict__ B4h, const uint4* __restrict__ B4l,
        const unsigned* __restrict__ off,
        const unsigned* __restrict__ bsum,
        const unsigned* __restrict__ cnts,
        const uint2* __restrict__ edat,
        const int* __restrict__ tgt,
        float* __restrict__ out, int n) {
    __shared__ uint4 afrag[2][256];      // A-fragments (h_t hi/lo), 8 KB
    __shared__ float Tl[16*132];         // T = H_t M, stride 132 vs banks, 8.25 KB
    int tid = threadIdx.x;
    int wave = tid >> 6, lane = tid & 63;
    int grp = lane >> 4;                 // node within wave (0..3)
    int l16 = lane & 15;
    int nid = wave * 4 + grp;            // node row 0..15
    int iw = blockIdx.x * 16 + nid;      // true node id
    int i = (iw < n) ? iw : (n - 1);     // clamped for safe addressing
    int t = tgt[0];
    t = (t < 0) ? 0 : (t > 2 ? 2 : t);

    // hoist all 3 relations' CSR ranges (uniform within each 16-lane group)
    int A[3], C[3];
#pragma unroll
    for (int r = 0; r < 3; ++r) {
        int seg = r*n + i;
        A[r] = (int)(off[seg] + bsum[seg >> 8]);
        C[r] = (int)cnts[seg];
    }

    // softmax stats for all 3 relations (per group; xor<=8 stays in-group)
    float m_[3], inv_[3];
#pragma unroll
    for (int r = 0; r < 3; ++r) {
        int cc = C[r];
        float m, s;
        if (cc <= 16) {
            float x = (l16 < cc) ? __uint_as_float(edat[A[r] + l16].y) : -INFINITY;
            m = x;
#pragma unroll
            for (int o = 8; o; o >>= 1) m = fmaxf(m, __shfl_xor(m, o));
            s = (l16 < cc) ? __expf(x - m) : 0.f;
#pragma unroll
            for (int o = 8; o; o >>= 1) s += __shfl_xor(s, o);
        } else {
            m = -INFINITY;
            for (int j = A[r] + l16; j < A[r] + cc; j += 16)
                m = fmaxf(m, __uint_as_float(edat[j].y));
#pragma unroll
            for (int o = 8; o; o >>= 1) m = fmaxf(m, __shfl_xor(m, o));
            s = 0.f;
            for (int j = A[r] + l16; j < A[r] + cc; j += 16)
                s += __expf(__uint_as_float(edat[j].y) - m);
#pragma unroll
            for (int o = 8; o; o >>= 1) s += __shfl_xor(s, o);
        }
        m_[r] = m; inv_[r] = 1.f / s;    // cc==0: unused (gather loop skipped)
    }

    float hr[3][8];
#pragma unroll
    for (int r = 0; r < 3; ++r) {
        f32x2 h2[4];
#pragma unroll
        for (int k = 0; k < 4; ++k) h2[k] = (f32x2){0.f, 0.f};
        int cc = C[r], a = A[r];
        float mm = m_[r], iv = inv_[r];
        // per-group gather, x4 unrolled: 4 independent row loads in flight.
        // edat read is a 16-lane same-address broadcast (L1 hit); no shfl.
        // packed f32x2 accumulation (v_pk_fma_f32).
        for (int p = 0; p < cc; p += 4) {
            int e1 = (p + 1 < cc) ? p + 1 : cc - 1;
            int e2 = (p + 2 < cc) ? p + 2 : cc - 1;
            int e3 = (p + 3 < cc) ? p + 3 : cc - 1;
            uint2 ed0 = edat[a + p];
            uint2 ed1 = edat[a + e1];
            uint2 ed2 = edat[a + e2];
            uint2 ed3 = edat[a + e3];
            uint4 v0 = Nbf[(size_t)ed0.x * 16 + l16];
            uint4 v1 = Nbf[(size_t)ed1.x * 16 + l16];
            uint4 v2 = Nbf[(size_t)ed2.x * 16 + l16];
            uint4 v3 = Nbf[(size_t)ed3.x * 16 + l16];
            float a0 = __expf(__uint_as_float(ed0.y) - mm) * iv;
            float a1 = (p + 1 < cc) ? __expf(__uint_as_float(ed1.y) - mm) * iv : 0.f;
            float a2 = (p + 2 < cc) ? __expf(__uint_as_float(ed2.y) - mm) * iv : 0.f;
            float a3 = (p + 3 < cc) ? __expf(__uint_as_float(ed3.y) - mm) * iv : 0.f;
            f32x2 A0 = (f32x2){a0, a0}, A1 = (f32x2){a1, a1};
            f32x2 A2 = (f32x2){a2, a2}, A3 = (f32x2){a3, a3};
            h2[0] += A0*unpk(v0.x) + A1*unpk(v1.x) + A2*unpk(v2.x) + A3*unpk(v3.x);
            h2[1] += A0*unpk(v0.y) + A1*unpk(v1.y) + A2*unpk(v2.y) + A3*unpk(v3.y);
            h2[2] += A0*unpk(v0.z) + A1*unpk(v1.z) + A2*unpk(v2.z) + A3*unpk(v3.z);
            h2[3] += A0*unpk(v0.w) + A1*unpk(v1.w) + A2*unpk(v2.w) + A3*unpk(v3.w);
        }
        // lane l16 owns dims 8*l16..+7 of its node — no cross-group reduce
#pragma unroll
        for (int k = 0; k < 4; ++k) {
            hr[r][2*k]   = h2[k].x;
            hr[r][2*k+1] = h2[k].y;
        }
        // A-fragment write (h_t hi/lo, fragment order), node-row = nid;
        // all 16 lanes of each group write their slot (256 writes/block).
        if (r == t) {
            unsigned ph[4], pl[4];
#pragma unroll
            for (int k = 0; k < 4; ++k) {
                unsigned short h0 = f2bf(h2[k].x);
                unsigned short h1 = f2bf(h2[k].y);
                unsigned short g0 = f2bf(h2[k].x - bflo(h0));
                unsigned short g1 = f2bf(h2[k].y - bflo(h1));
                ph[k] = (unsigned)h0 | ((unsigned)h1 << 16);
                pl[k] = (unsigned)g0 | ((unsigned)g1 << 16);
            }
            int u = uswz(((l16 >> 2) * 64) + ((l16 & 3) * 16) + nid);
            afrag[0][u] = make_uint4(ph[0], ph[1], ph[2], ph[3]);
            afrag[1][u] = make_uint4(pl[0], pl[1], pl[2], pl[3]);
        }
    }
    __syncthreads();

    // T = Ah*Bh + Al*Bh + Ah*Bl ; wave w owns j-tiles 2w, 2w+1.
    {
        int qm = lane >> 4;              // C/D row group 0..3
        f32x4 acc0 = {0.f, 0.f, 0.f, 0.f};
        f32x4 acc1 = {0.f, 0.f, 0.f, 0.f};
        int jt0 = wave*2, jt1 = wave*2 + 1;
        for (int ks = 0; ks < 4; ++ks) {
            uint4 a_hi = afrag[0][uswz(ks*64 + lane)];
            uint4 a_lo = afrag[1][uswz(ks*64 + lane)];
            uint4 b0h = B4h[(jt0*4 + ks)*64 + lane];
            uint4 b0l = B4l[(jt0*4 + ks)*64 + lane];
            uint4 b1h = B4h[(jt1*4 + ks)*64 + lane];
            uint4 b1l = B4l[(jt1*4 + ks)*64 + lane];
            acc0 = MFMA(__builtin_bit_cast(short8, a_hi),
                        __builtin_bit_cast(short8, b0h), acc0);
            acc1 = MFMA(__builtin_bit_cast(short8, a_hi),
                        __builtin_bit_cast(short8, b1h), acc1);
            acc0 = MFMA(__builtin_bit_cast(short8, a_lo),
                        __builtin_bit_cast(short8, b0h), acc0);
            acc1 = MFMA(__builtin_bit_cast(short8, a_lo),
                        __builtin_bit_cast(short8, b1h), acc1);
            acc0 = MFMA(__builtin_bit_cast(short8, a_hi),
                        __builtin_bit_cast(short8, b0l), acc0);
            acc1 = MFMA(__builtin_bit_cast(short8, a_hi),
                        __builtin_bit_cast(short8, b1l), acc1);
        }
        // C/D layout: col = lane&15, row = (lane>>4)*4 + reg  [verified]
        int col0 = jt0*16 + l16, col1 = jt1*16 + l16;
#pragma unroll
        for (int rg = 0; rg < 4; ++rg) {
            Tl[(qm*4 + rg)*132 + col0] = acc0[rg];
            Tl[(qm*4 + rg)*132 + col1] = acc1[rg];
        }
    }
    __syncthreads();

    // each group reads its node's T row: lane l16 -> dims 8*l16..+7
    float4 ta = *(const float4*)&Tl[nid*132 + 8*l16];
    float4 tb = *(const float4*)&Tl[nid*132 + 8*l16 + 4];
    float t8[8] = {ta.x, ta.y, ta.z, ta.w, tb.x, tb.y, tb.z, tb.w};

    const float inv = 0.088388347648318447f;   // 1/sqrt(128)
    float e[3];
#pragma unroll
    for (int r = 0; r < 3; ++r) {
        float v = 0.f;
#pragma unroll
        for (int k = 0; k < 8; ++k) v += t8[k]*hr[r][k];
#pragma unroll
        for (int o = 8; o; o >>= 1) v += __shfl_xor(v, o);   // over l16
        e[r] = v * inv;
    }
    float mx = fmaxf(e[0], fmaxf(e[1], e[2]));
    float x0 = __expf(e[0]-mx), x1 = __expf(e[1]-mx), x2 = __expf(e[2]-mx);
    float sinv = 1.f / (x0 + x1 + x2);
    float aw0 = x0*sinv, aw1 = x1*sinv, aw2 = x2*sinv;
    if (iw < n) {
        float4 oa, ob;
        oa.x = aw0*hr[0][0] + aw1*hr[1][0] + aw2*hr[2][0];
        oa.y = aw0*hr[0][1] + aw1*hr[1][1] + aw2*hr[2][1];
        oa.z = aw0*hr[0][2] + aw1*hr[1][2] + aw2*hr[2][2];
        oa.w = aw0*hr[0][3] + aw1*hr[1][3] + aw2*hr[2][3];
        ob.x = aw0*hr[0][4] + aw1*hr[1][4] + aw2*hr[2][4];
        ob.y = aw0*hr[0][5] + aw1*hr[1][5] + aw2*hr[2][5];
        ob.z = aw0*hr[0][6] + aw1*hr[1][6] + aw2*hr[2][6];
        ob.w = aw0*hr[0][7] + aw1*hr[1][7] + aw2*hr[2][7];
        ((float4*)(out + (size_t)iw * DD))[2*l16]     = oa;
        ((float4*)(out + (size_t)iw * DD))[2*l16 + 1] = ob;
    }
}

// ---------------------------------------------------------------------------
extern "C" void kernel_launch(void* const* d_in, const int* in_sizes, int n_in,
                              void* d_out, int out_size, void* d_ws, size_t ws_size,
                              hipStream_t stream) {
    float* outp = (float*)d_out;
    int fillgrid = (out_size + 255) / 256;
    if (n_in != 17) {                                  // marker: 1024.0
        k_fill<<<fillgrid, 256, 0, stream>>>(outp, 1024.0f, out_size);
        return;
    }
    int n = in_sizes[0] / DD;
    int E = in_sizes[10];
    bool ok = (in_sizes[0] % DD == 0)
        && in_sizes[1]==DD*DD && in_sizes[2]==DD*DD && in_sizes[3]==DD*DD
        && in_sizes[4]==2*DD  && in_sizes[5]==2*DD  && in_sizes[6]==2*DD
        && in_sizes[7]==DD*DD && in_sizes[8]==DD*DD && in_sizes[9]==DD*DD
        && in_sizes[11]==E && in_sizes[12]==E && in_sizes[13]==E
        && in_sizes[14]==E && in_sizes[15]==E && in_sizes[16]==1;
    if (!ok) {                                         // marker: 512.0
        k_fill<<<fillgrid, 256, 0, stream>>>(outp, 512.0f, out_size);
        return;
    }
    int SEG = 3*n;
    int NB1 = (SEG + 255) / 256;
    int tot = 3*E;

    // ws (floats): sl[3n] sr[3n] uv[768] Bh+Bl[DD*DD floats as ushort]
    //              off[3n] bsum[NB1] cnts[3n] rank[3E]
    //              | edat[3E]x2 (8B) | Nbf[n*64] (16B)
    size_t o_edat = (size_t)2*SEG + 768 + DD*DD + (size_t)SEG + NB1
                  + (size_t)SEG + (size_t)tot;
    o_edat = (o_edat + 1) & ~(size_t)1;
    size_t o_nbf = o_edat + (size_t)2*tot;
    o_nbf = (o_nbf + 3) & ~(size_t)3;
    size_t need_f = o_nbf + (size_t)n*64;
    if (ws_size < need_f * sizeof(float)) {            // marker: 256.0
        k_fill<<<fillgrid, 256, 0, stream>>>(outp, 256.0f, out_size);
        return;
    }

    const float* N   = (const float*)d_in[0];
    const float* W10 = (const float*)d_in[1];
    const float* W11 = (const float*)d_in[2];
    const float* W12 = (const float*)d_in[3];
    const float* w20 = (const float*)d_in[4];
    const float* w21 = (const float*)d_in[5];
    const float* w22 = (const float*)d_in[6];
    const float* Wq  = (const float*)d_in[7];
    const float* Wk  = (const float*)d_in[8];
    // d_in[9] = Wv — unused in the reference output
    const int* s0 = (const int*)d_in[10];
    const int* d0 = (const int*)d_in[11];
    const int* s1 = (const int*)d_in[12];
    const int* d1 = (const int*)d_in[13];
    const int* s2 = (const int*)d_in[14];
    const int* d2 = (const int*)d_in[15];
    const int* tgt = (const int*)d_in[16];

    float* ws = (float*)d_ws;
    float* sl = ws;
    float* sr = sl + SEG;
    float* uv = sr + SEG;
    unsigned short* Bh = (unsigned short*)(uv + 768);   // 16384 bf16 (32 KB)
    unsigned short* Bl = Bh + DD*DD;                    // 16384 bf16 (32 KB)
    unsigned* off  = (unsigned*)(uv + 768 + DD*DD);     // counters -> tile-excl
    unsigned* bsum = off + SEG;                         // tile totals -> excl
    unsigned* cnts = bsum + NB1;                        // per-segment counts
    unsigned* rank = cnts + SEG;
    uint2*    edat = (uint2*)(ws + o_edat);
    unsigned* Nbf  = (unsigned*)(ws + o_nbf);

    int NZ  = SEG;                                     // zero off only
    int NBZ = (NZ + DD - 1) / DD;
    int gridS = (n + 7) / 8;                           // score blocks
    int gridC = (tot + 255) / 256;                     // count threads coverage
    if (gridC > gridS) gridS = gridC;

    k_prep<<<DD + 3 + NBZ, DD, 0, stream>>>(Wq, Wk, W10, W11, W12,
                                            w20, w21, w22, Bh, Bl, uv, off, NZ);
    k_scores<<<gridS, 256, 0, stream>>>(N, uv, sl, sr, (uint2*)Nbf, off, rank,
                                        d0, d1, d2, n, E);
    k_scan1<<<NB1, 256, 0, stream>>>(off, bsum, cnts, SEG);
    k_scan2<<<1, 256, 0, stream>>>(bsum, NB1);
    k_scatter<<<(tot + 255)/256, 256, 0, stream>>>(s0,d0,s1,d1,s2,d2, sl,sr,
                                                   off, bsum, rank, edat, n, E);
    k_node<<<(n + 15)/16, 256, 0, stream>>>((const uint4*)Nbf,
                                            (const uint4*)Bh, (const uint4*)Bl,
                                            off, bsum, cnts, edat, tgt, outp, n);
}

// Round 14
// 365.844 us; speedup vs baseline: 1.0684x; 1.0144x over previous
//
#include <hip/hip_runtime.h>
#include <hip/hip_bf16.h>
#include <math.h>

#define DD 128

typedef __attribute__((ext_vector_type(8))) short short8;
typedef __attribute__((ext_vector_type(4))) float f32x4;
typedef __attribute__((ext_vector_type(2))) float f32x2;

static __device__ __forceinline__ unsigned short f2bf(float f) {
    unsigned u = __float_as_uint(f);
    u += 0x7fffu + ((u >> 16) & 1u);   // RNE
    return (unsigned short)(u >> 16);
}
static __device__ __forceinline__ float bflo(unsigned mm) { return __uint_as_float(mm << 16); }
static __device__ __forceinline__ float bfhi(unsigned mm) { return __uint_as_float(mm & 0xffff0000u); }
// unpack a dword of 2 bf16 into packed f32x2 (feeds v_pk_fma_f32)
static __device__ __forceinline__ f32x2 unpk(unsigned w) {
    f32x2 r; r.x = __uint_as_float(w << 16); r.y = __uint_as_float(w & 0xffff0000u);
    return r;
}

static __device__ __forceinline__ f32x4 MFMA(short8 a, short8 b, f32x4 c) {
    return __builtin_amdgcn_mfma_f32_16x16x32_bf16(a, b, c, 0, 0, 0);
}
// involution swizzle on 16B-unit index: spreads A-frag writer banks, reader stays conflict-free
static __device__ __forceinline__ int uswz(int u) { return u ^ ((u >> 4) & 7); }

// diagnostic marker fill
__global__ void k_fill(float* __restrict__ out, float v, int n) {
    int i = blockIdx.x * 256 + threadIdx.x;
    if (i < n) out[i] = v;
}

// ---------------------------------------------------------------------------
// fused prep: blocks 0..127   -> M[c][j] = sum_k Wq[k][c]*Wk[k][j] in MFMA
//                                B-fragment order, bf16 hi/lo (Bh/Bl)
//             blocks 128..130 -> u_r/v_r folds
//             blocks 131..    -> zero CSR counters (SEG words)
__global__ void k_prep(const float* __restrict__ Wq, const float* __restrict__ Wk,
                       const float* __restrict__ W10, const float* __restrict__ W11,
                       const float* __restrict__ W12,
                       const float* __restrict__ w20, const float* __restrict__ w21,
                       const float* __restrict__ w22,
                       unsigned short* __restrict__ Bh, unsigned short* __restrict__ Bl,
                       float* __restrict__ uv, unsigned* __restrict__ cnt, int NZ) {
    int b = blockIdx.x, j = threadIdx.x;
    if (b < DD) {
        float acc = 0.f;
        for (int k = 0; k < DD; ++k)
            acc += Wq[k*DD + b] * Wk[k*DD + j];
        unsigned short hi = f2bf(acc);
        unsigned short lo = f2bf(acc - bflo(hi));
        // B-frag: lane l holds B[ks*32 + 8*(l>>4) + jj][t*16 + (l&15)], jj=0..7
        int t  = j >> 4;
        int ks = b >> 5;
        int l  = ((b >> 3) & 3) * 16 + (j & 15);
        int jj = b & 7;
        int idx = ((t*4 + ks)*64 + l)*8 + jj;
        Bh[idx] = hi;
        Bl[idx] = lo;
    } else if (b < DD + 3) {
        int r = b - DD;
        const float* W1 = (r==0) ? W10 : (r==1 ? W11 : W12);
        const float* w2 = (r==0) ? w20 : (r==1 ? w21 : w22);
        float u = 0.f, v = 0.f;
        for (int k = 0; k < DD; ++k) {
            float w = W1[k*DD + j];
            u += w2[k]      * w;
            v += w2[DD + k] * w;
        }
        uv[r*256 + j]      = u;
        uv[r*256 + DD + j] = v;
    } else {
        int idx = (b - (DD + 3)) * DD + j;
        if (idx < NZ) cnt[idx] = 0u;
    }
}

// ---------------------------------------------------------------------------
// k_scores (+fused count): 2 nodes/wave (half-wave float4) for per-node
// score folds + bf16 N copy; additionally thread g < 3E does the per-edge
// degree count + rank (atomics hide under the N stream). cnt is pre-zeroed
// by k_prep (k_scores already depends on k_prep via uv).
__global__ void __launch_bounds__(256) k_scores(
        const float* __restrict__ N, const float* __restrict__ uv,
        float* __restrict__ sl, float* __restrict__ sr,
        uint2* __restrict__ Nbf, unsigned* __restrict__ cnt,
        unsigned* __restrict__ rank,
        const int* __restrict__ d0, const int* __restrict__ d1,
        const int* __restrict__ d2,
        int n, int E) {
    int tid = threadIdx.x;
    int g = blockIdx.x * 256 + tid;
    if (g < 3*E) {                       // fused k_count
        int r = (g >= 2*E) ? 2 : (g >= E ? 1 : 0);
        int e = g - r*E;
        const int* Dd = (r==0) ? d0 : (r==1 ? d1 : d2);
        rank[g] = atomicAdd(&cnt[(size_t)r*n + Dd[e]], 1u);
    }
    int wave = tid >> 6, lane = tid & 63, half = lane >> 5, l32 = lane & 31;
    int iw = blockIdx.x * 8 + wave * 2 + half;
    if (iw >= n && blockIdx.x * 8 >= n) return;   // pure-count tail blocks
    int i = (iw < n) ? iw : (n - 1);
    float4 nv = ((const float4*)N)[(size_t)i * 32 + l32];
    if (iw < n) {
        uint2 pk;
        pk.x = (unsigned)f2bf(nv.x) | ((unsigned)f2bf(nv.y) << 16);
        pk.y = (unsigned)f2bf(nv.z) | ((unsigned)f2bf(nv.w) << 16);
        Nbf[(size_t)iw * 32 + l32] = pk;
    }
    const float4* UV4 = (const float4*)uv;
    float acc[6];
#pragma unroll
    for (int r = 0; r < 3; ++r) {
        float4 u = UV4[r*64 + l32];
        float4 v = UV4[r*64 + 32 + l32];
        acc[2*r]   = nv.x*u.x + nv.y*u.y + nv.z*u.z + nv.w*u.w;
        acc[2*r+1] = nv.x*v.x + nv.y*v.y + nv.z*v.z + nv.w*v.w;
    }
#pragma unroll
    for (int o = 16; o; o >>= 1) {
#pragma unroll
        for (int q = 0; q < 6; ++q) acc[q] += __shfl_xor(acc[q], o);
    }
    if (l32 == 0 && iw < n) {
#pragma unroll
        for (int r = 0; r < 3; ++r) {
            sl[(size_t)r*n + iw] = acc[2*r];
            sr[(size_t)r*n + iw] = acc[2*r+1];
        }
    }
}

// ---------------------------------------------------------------------------
// k_scan1: per-tile exclusive scan; also emits per-segment counts (cnts)
// so downstream range-hoists need one broadcast load per segment instead
// of reading off[seg+1]. [scanA's global-cursor variant cost +12us on the
// blob (confirmed R11+R12) — two-kernel chain retained.]
__global__ void __launch_bounds__(256) k_scan1(unsigned* __restrict__ off,
                                               unsigned* __restrict__ bsum,
                                               unsigned* __restrict__ cnts,
                                               int SEG) {
    __shared__ unsigned s[256];
    int tid = threadIdx.x;
    int i = blockIdx.x * 256 + tid;
    unsigned v = (i < SEG) ? off[i] : 0u;
    s[tid] = v; __syncthreads();
#pragma unroll
    for (int o = 1; o < 256; o <<= 1) {
        unsigned a = (tid >= o) ? s[tid - o] : 0u; __syncthreads();
        s[tid] += a; __syncthreads();
    }
    if (i < SEG) {
        off[i]  = s[tid] - v;          // exclusive within tile
        cnts[i] = v;                   // per-segment count
    }
    if (tid == 255) bsum[blockIdx.x] = s[255]; // tile total
}

__global__ void __launch_bounds__(256) k_scan2(unsigned* __restrict__ bsum, int nb) {
    __shared__ unsigned s[256];
    __shared__ unsigned carry;
    int tid = threadIdx.x;
    if (tid == 0) carry = 0u;
    for (int base = 0; base < nb; base += 256) {
        int i = base + tid;
        unsigned v = (i < nb) ? bsum[i] : 0u;
        __syncthreads();
        s[tid] = v; __syncthreads();
#pragma unroll
        for (int o = 1; o < 256; o <<= 1) {
            unsigned a = (tid >= o) ? s[tid - o] : 0u; __syncthreads();
            s[tid] += a; __syncthreads();
        }
        unsigned incl = s[tid], tot = s[255], c = carry;
        if (i < nb) bsum[i] = c + incl - v;    // exclusive across tiles
        __syncthreads();
        if (tid == 0) carry = c + tot;
    }
}

// scatter with precomputed rank — no atomics
__global__ void k_scatter(const int* __restrict__ s0, const int* __restrict__ d0,
                          const int* __restrict__ s1, const int* __restrict__ d1,
                          const int* __restrict__ s2, const int* __restrict__ d2,
                          const float* __restrict__ sl, const float* __restrict__ sr,
                          const unsigned* __restrict__ off,
                          const unsigned* __restrict__ bsum,
                          const unsigned* __restrict__ rank,
                          uint2* __restrict__ edat, int n, int E) {
    int g = blockIdx.x * 256 + threadIdx.x;
    if (g >= 3*E) return;
    int r = (g >= 2*E) ? 2 : (g >= E ? 1 : 0);
    int e = g - r*E;
    const int* S  = (r==0) ? s0 : (r==1 ? s1 : s2);
    const int* Dd = (r==0) ? d0 : (r==1 ? d1 : d2);
    int si = S[e], di = Dd[e];
    int seg = r*n + di;
    float x = sl[(size_t)r*n + si] + sr[seg];
    x = (x >= 0.f) ? x : 0.01f * x;            // leaky_relu
    unsigned p = off[seg] + bsum[seg >> 8] + rank[g];
    edat[p] = make_uint2((unsigned)si, __float_as_uint(x));
}

// ---------------------------------------------------------------------------
// k_node: fused per-node pass, 256 threads, FOUR nodes per wave (one per
// 16-lane group) -> 16 nodes/block. [R13 base — proven 107.6us] + BRANCH-
// FREE stats: the first-16 edge loads for ALL 3 relations are issued in one
// unconditional straight-line loop (the old per-relation if/else + unknown-
// trip loops serialized 3 load latencies; now they co-issue). cc>16 is a
// rare group-uniform tail (P~0.04% at Poisson-6 degree). 1/s is DEFERRED:
// the gather accumulates unnormalized exp(x-m)*v, one packed multiply by iv
// afterwards — s's shfl chain and the rcp come off the stats->gather
// critical path. iv = (cc>0) ? 1/s : 0 keeps empty segments at h=0.
__global__ void __launch_bounds__(256, 4) k_node(
        const uint4* __restrict__ Nbf,
        const uint4* __restrict__ B4h, const uint4* __restrict__ B4l,
        const unsigned* __restrict__ off,
        const unsigned* __restrict__ bsum,
        const unsigned* __restrict__ cnts,
        const uint2* __restrict__ edat,
        const int* __restrict__ tgt,
        float* __restrict__ out, int n) {
    __shared__ uint4 afrag[2][256];      // A-fragments (h_t hi/lo), 8 KB
    __shared__ float Tl[16*132];         // T = H_t M, stride 132 vs banks, 8.25 KB
    int tid = threadIdx.x;
    int wave = tid >> 6, lane = tid & 63;
    int grp = lane >> 4;                 // node within wave (0..3)
    int l16 = lane & 15;
    int nid = wave * 4 + grp;            // node row 0..15
    int iw = blockIdx.x * 16 + nid;      // true node id
    int i = (iw < n) ? iw : (n - 1);     // clamped for safe addressing
    int t = tgt[0];
    t = (t < 0) ? 0 : (t > 2 ? 2 : t);

    // hoist all 3 relations' CSR ranges (uniform within each 16-lane group)
    int A[3], C[3];
#pragma unroll
    for (int r = 0; r < 3; ++r) {
        int seg = r*n + i;
        A[r] = (int)(off[seg] + bsum[seg >> 8]);
        C[r] = (int)cnts[seg];
    }

    // straight-line first-16 loads for all 3 relations (co-issued; the
    // clamped address is always in-bounds of the workspace, value masked)
    float xf[3];
#pragma unroll
    for (int r = 0; r < 3; ++r) {
        int cc = C[r];
        int idx = (l16 < cc) ? l16 : (cc > 0 ? cc - 1 : 0);
        uint2 d = edat[A[r] + idx];
        xf[r] = (l16 < cc) ? __uint_as_float(d.y) : -INFINITY;
    }

    // softmax stats (per group; xor<=8 stays in-group); rare cc>16 tail
    float m_[3], inv_[3];
#pragma unroll
    for (int r = 0; r < 3; ++r) {
        int cc = C[r];
        float m = xf[r];
#pragma unroll
        for (int o = 8; o; o >>= 1) m = fmaxf(m, __shfl_xor(m, o));
        if (cc > 16) {
            float mt = -INFINITY;
            for (int j = A[r] + 16 + l16; j < A[r] + cc; j += 16)
                mt = fmaxf(mt, __uint_as_float(edat[j].y));
#pragma unroll
            for (int o = 8; o; o >>= 1) mt = fmaxf(mt, __shfl_xor(mt, o));
            m = fmaxf(m, mt);
        }
        float s = (l16 < cc) ? __expf(xf[r] - m) : 0.f;
        if (cc > 16) {
            for (int j = A[r] + 16 + l16; j < A[r] + cc; j += 16)
                s += __expf(__uint_as_float(edat[j].y) - m);
        }
#pragma unroll
        for (int o = 8; o; o >>= 1) s += __shfl_xor(s, o);
        m_[r] = m;
        inv_[r] = (cc > 0) ? 1.f / s : 0.f;
    }

    float hr[3][8];
#pragma unroll
    for (int r = 0; r < 3; ++r) {
        f32x2 h2[4];
#pragma unroll
        for (int k = 0; k < 4; ++k) h2[k] = (f32x2){0.f, 0.f};
        int cc = C[r], a = A[r];
        float mm = m_[r];
        // per-group gather, x4 unrolled: 4 independent row loads in flight.
        // edat read is a 16-lane same-address broadcast (L1 hit); no shfl.
        // UNNORMALIZED packed-f32 accumulation; iv applied once after.
        for (int p = 0; p < cc; p += 4) {
            int e1 = (p + 1 < cc) ? p + 1 : cc - 1;
            int e2 = (p + 2 < cc) ? p + 2 : cc - 1;
            int e3 = (p + 3 < cc) ? p + 3 : cc - 1;
            uint2 ed0 = edat[a + p];
            uint2 ed1 = edat[a + e1];
            uint2 ed2 = edat[a + e2];
            uint2 ed3 = edat[a + e3];
            uint4 v0 = Nbf[(size_t)ed0.x * 16 + l16];
            uint4 v1 = Nbf[(size_t)ed1.x * 16 + l16];
            uint4 v2 = Nbf[(size_t)ed2.x * 16 + l16];
            uint4 v3 = Nbf[(size_t)ed3.x * 16 + l16];
            float a0 = __expf(__uint_as_float(ed0.y) - mm);
            float a1 = (p + 1 < cc) ? __expf(__uint_as_float(ed1.y) - mm) : 0.f;
            float a2 = (p + 2 < cc) ? __expf(__uint_as_float(ed2.y) - mm) : 0.f;
            float a3 = (p + 3 < cc) ? __expf(__uint_as_float(ed3.y) - mm) : 0.f;
            f32x2 A0 = (f32x2){a0, a0}, A1 = (f32x2){a1, a1};
            f32x2 A2 = (f32x2){a2, a2}, A3 = (f32x2){a3, a3};
            h2[0] += A0*unpk(v0.x) + A1*unpk(v1.x) + A2*unpk(v2.x) + A3*unpk(v3.x);
            h2[1] += A0*unpk(v0.y) + A1*unpk(v1.y) + A2*unpk(v2.y) + A3*unpk(v3.y);
            h2[2] += A0*unpk(v0.z) + A1*unpk(v1.z) + A2*unpk(v2.z) + A3*unpk(v3.z);
            h2[3] += A0*unpk(v0.w) + A1*unpk(v1.w) + A2*unpk(v2.w) + A3*unpk(v3.w);
        }
        // apply deferred normalization (empty segment: iv=0 -> h=0)
        {
            f32x2 IV = (f32x2){inv_[r], inv_[r]};
#pragma unroll
            for (int k = 0; k < 4; ++k) h2[k] = h2[k] * IV;
        }
        // lane l16 owns dims 8*l16..+7 of its node — no cross-group reduce
#pragma unroll
        for (int k = 0; k < 4; ++k) {
            hr[r][2*k]   = h2[k].x;
            hr[r][2*k+1] = h2[k].y;
        }
        // A-fragment write (h_t hi/lo, fragment order), node-row = nid;
        // all 16 lanes of each group write their slot (256 writes/block).
        if (r == t) {
            unsigned ph[4], pl[4];
#pragma unroll
            for (int k = 0; k < 4; ++k) {
                unsigned short h0 = f2bf(h2[k].x);
                unsigned short h1 = f2bf(h2[k].y);
                unsigned short g0 = f2bf(h2[k].x - bflo(h0));
                unsigned short g1 = f2bf(h2[k].y - bflo(h1));
                ph[k] = (unsigned)h0 | ((unsigned)h1 << 16);
                pl[k] = (unsigned)g0 | ((unsigned)g1 << 16);
            }
            int u = uswz(((l16 >> 2) * 64) + ((l16 & 3) * 16) + nid);
            afrag[0][u] = make_uint4(ph[0], ph[1], ph[2], ph[3]);
            afrag[1][u] = make_uint4(pl[0], pl[1], pl[2], pl[3]);
        }
    }
    __syncthreads();

    // T = Ah*Bh + Al*Bh + Ah*Bl ; wave w owns j-tiles 2w, 2w+1.
    {
        int qm = lane >> 4;              // C/D row group 0..3
        f32x4 acc0 = {0.f, 0.f, 0.f, 0.f};
        f32x4 acc1 = {0.f, 0.f, 0.f, 0.f};
        int jt0 = wave*2, jt1 = wave*2 + 1;
        for (int ks = 0; ks < 4; ++ks) {
            uint4 a_hi = afrag[0][uswz(ks*64 + lane)];
            uint4 a_lo = afrag[1][uswz(ks*64 + lane)];
            uint4 b0h = B4h[(jt0*4 + ks)*64 + lane];
            uint4 b0l = B4l[(jt0*4 + ks)*64 + lane];
            uint4 b1h = B4h[(jt1*4 + ks)*64 + lane];
            uint4 b1l = B4l[(jt1*4 + ks)*64 + lane];
            acc0 = MFMA(__builtin_bit_cast(short8, a_hi),
                        __builtin_bit_cast(short8, b0h), acc0);
            acc1 = MFMA(__builtin_bit_cast(short8, a_hi),
                        __builtin_bit_cast(short8, b1h), acc1);
            acc0 = MFMA(__builtin_bit_cast(short8, a_lo),
                        __builtin_bit_cast(short8, b0h), acc0);
            acc1 = MFMA(__builtin_bit_cast(short8, a_lo),
                        __builtin_bit_cast(short8, b1h), acc1);
            acc0 = MFMA(__builtin_bit_cast(short8, a_hi),
                        __builtin_bit_cast(short8, b0l), acc0);
            acc1 = MFMA(__builtin_bit_cast(short8, a_hi),
                        __builtin_bit_cast(short8, b1l), acc1);
        }
        // C/D layout: col = lane&15, row = (lane>>4)*4 + reg  [verified]
        int col0 = jt0*16 + l16, col1 = jt1*16 + l16;
#pragma unroll
        for (int rg = 0; rg < 4; ++rg) {
            Tl[(qm*4 + rg)*132 + col0] = acc0[rg];
            Tl[(qm*4 + rg)*132 + col1] = acc1[rg];
        }
    }
    __syncthreads();

    // each group reads its node's T row: lane l16 -> dims 8*l16..+7
    float4 ta = *(const float4*)&Tl[nid*132 + 8*l16];
    float4 tb = *(const float4*)&Tl[nid*132 + 8*l16 + 4];
    float t8[8] = {ta.x, ta.y, ta.z, ta.w, tb.x, tb.y, tb.z, tb.w};

    const float inv = 0.088388347648318447f;   // 1/sqrt(128)
    float e[3];
#pragma unroll
    for (int r = 0; r < 3; ++r) {
        float v = 0.f;
#pragma unroll
        for (int k = 0; k < 8; ++k) v += t8[k]*hr[r][k];
#pragma unroll
        for (int o = 8; o; o >>= 1) v += __shfl_xor(v, o);   // over l16
        e[r] = v * inv;
    }
    float mx = fmaxf(e[0], fmaxf(e[1], e[2]));
    float x0 = __expf(e[0]-mx), x1 = __expf(e[1]-mx), x2 = __expf(e[2]-mx);
    float sinv = 1.f / (x0 + x1 + x2);
    float aw0 = x0*sinv, aw1 = x1*sinv, aw2 = x2*sinv;
    if (iw < n) {
        float4 oa, ob;
        oa.x = aw0*hr[0][0] + aw1*hr[1][0] + aw2*hr[2][0];
        oa.y = aw0*hr[0][1] + aw1*hr[1][1] + aw2*hr[2][1];
        oa.z = aw0*hr[0][2] + aw1*hr[1][2] + aw2*hr[2][2];
        oa.w = aw0*hr[0][3] + aw1*hr[1][3] + aw2*hr[2][3];
        ob.x = aw0*hr[0][4] + aw1*hr[1][4] + aw2*hr[2][4];
        ob.y = aw0*hr[0][5] + aw1*hr[1][5] + aw2*hr[2][5];
        ob.z = aw0*hr[0][6] + aw1*hr[1][6] + aw2*hr[2][6];
        ob.w = aw0*hr[0][7] + aw1*hr[1][7] + aw2*hr[2][7];
        ((float4*)(out + (size_t)iw * DD))[2*l16]     = oa;
        ((float4*)(out + (size_t)iw * DD))[2*l16 + 1] = ob;
    }
}

// ---------------------------------------------------------------------------
extern "C" void kernel_launch(void* const* d_in, const int* in_sizes, int n_in,
                              void* d_out, int out_size, void* d_ws, size_t ws_size,
                              hipStream_t stream) {
    float* outp = (float*)d_out;
    int fillgrid = (out_size + 255) / 256;
    if (n_in != 17) {                                  // marker: 1024.0
        k_fill<<<fillgrid, 256, 0, stream>>>(outp, 1024.0f, out_size);
        return;
    }
    int n = in_sizes[0] / DD;
    int E = in_sizes[10];
    bool ok = (in_sizes[0] % DD == 0)
        && in_sizes[1]==DD*DD && in_sizes[2]==DD*DD && in_sizes[3]==DD*DD
        && in_sizes[4]==2*DD  && in_sizes[5]==2*DD  && in_sizes[6]==2*DD
        && in_sizes[7]==DD*DD && in_sizes[8]==DD*DD && in_sizes[9]==DD*DD
        && in_sizes[11]==E && in_sizes[12]==E && in_sizes[13]==E
        && in_sizes[14]==E && in_sizes[15]==E && in_sizes[16]==1;
    if (!ok) {                                         // marker: 512.0
        k_fill<<<fillgrid, 256, 0, stream>>>(outp, 512.0f, out_size);
        return;
    }
    int SEG = 3*n;
    int NB1 = (SEG + 255) / 256;
    int tot = 3*E;

    // ws (floats): sl[3n] sr[3n] uv[768] Bh+Bl[DD*DD floats as ushort]
    //              off[3n] bsum[NB1] cnts[3n] rank[3E]
    //              | edat[3E]x2 (8B) | Nbf[n*64] (16B)
    size_t o_edat = (size_t)2*SEG + 768 + DD*DD + (size_t)SEG + NB1
                  + (size_t)SEG + (size_t)tot;
    o_edat = (o_edat + 1) & ~(size_t)1;
    size_t o_nbf = o_edat + (size_t)2*tot;
    o_nbf = (o_nbf + 3) & ~(size_t)3;
    size_t need_f = o_nbf + (size_t)n*64;
    if (ws_size < need_f * sizeof(float)) {            // marker: 256.0
        k_fill<<<fillgrid, 256, 0, stream>>>(outp, 256.0f, out_size);
        return;
    }

    const float* N   = (const float*)d_in[0];
    const float* W10 = (const float*)d_in[1];
    const float* W11 = (const float*)d_in[2];
    const float* W12 = (const float*)d_in[3];
    const float* w20 = (const float*)d_in[4];
    const float* w21 = (const float*)d_in[5];
    const float* w22 = (const float*)d_in[6];
    const float* Wq  = (const float*)d_in[7];
    const float* Wk  = (const float*)d_in[8];
    // d_in[9] = Wv — unused in the reference output
    const int* s0 = (const int*)d_in[10];
    const int* d0 = (const int*)d_in[11];
    const int* s1 = (const int*)d_in[12];
    const int* d1 = (const int*)d_in[13];
    const int* s2 = (const int*)d_in[14];
    const int* d2 = (const int*)d_in[15];
    const int* tgt = (const int*)d_in[16];

    float* ws = (float*)d_ws;
    float* sl = ws;
    float* sr = sl + SEG;
    float* uv = sr + SEG;
    unsigned short* Bh = (unsigned short*)(uv + 768);   // 16384 bf16 (32 KB)
    unsigned short* Bl = Bh + DD*DD;                    // 16384 bf16 (32 KB)
    unsigned* off  = (unsigned*)(uv + 768 + DD*DD);     // counters -> tile-excl
    unsigned* bsum = off + SEG;                         // tile totals -> excl
    unsigned* cnts = bsum + NB1;                        // per-segment counts
    unsigned* rank = cnts + SEG;
    uint2*    edat = (uint2*)(ws + o_edat);
    unsigned* Nbf  = (unsigned*)(ws + o_nbf);

    int NZ  = SEG;                                     // zero off only
    int NBZ = (NZ + DD - 1) / DD;
    int gridS = (n + 7) / 8;                           // score blocks
    int gridC = (tot + 255) / 256;                     // count threads coverage
    if (gridC > gridS) gridS = gridC;

    k_prep<<<DD + 3 + NBZ, DD, 0, stream>>>(Wq, Wk, W10, W11, W12,
                                            w20, w21, w22, Bh, Bl, uv, off, NZ);
    k_scores<<<gridS, 256, 0, stream>>>(N, uv, sl, sr, (uint2*)Nbf, off, rank,
                                        d0, d1, d2, n, E);
    k_scan1<<<NB1, 256, 0, stream>>>(off, bsum, cnts, SEG);
    k_scan2<<<1, 256, 0, stream>>>(bsum, NB1);
    k_scatter<<<(tot + 255)/256, 256, 0, stream>>>(s0,d0,s1,d1,s2,d2, sl,sr,
                                                   off, bsum, rank, edat, n, E);
    k_node<<<(n + 15)/16, 256, 0, stream>>>((const uint4*)Nbf,
                                            (const uint4*)Bh, (const uint4*)Bl,
                                            off, bsum, cnts, edat, tgt, outp, n);
}